// Round 1
// baseline (3291.665 us; speedup 1.0000x reference)
//
#include <hip/hip_runtime.h>

#define S_LEN 2048
#define DIN   50
#define DPAD  52
#define H     64

// tanh(v) = 1 - 2/(exp(2v)+1); exact at +/-inf, ~1e-6 rel err via v_exp_f32
__device__ __forceinline__ float tanh_fast(float v) {
    float e = __expf(2.0f * v);
    return 1.0f - 2.0f / (e + 1.0f);
}

__global__ __launch_bounds__(64, 1)
void rnn_fused(const float* __restrict__ x,
               const float* __restrict__ W_ih0, const float* __restrict__ W_hh0,
               const float* __restrict__ b_ih0, const float* __restrict__ b_hh0,
               const float* __restrict__ W_ih1, const float* __restrict__ W_hh1,
               const float* __restrict__ b_ih1, const float* __restrict__ b_hh1,
               const float* __restrict__ W1, const float* __restrict__ b1,
               const float* __restrict__ W2, const float* __restrict__ b2,
               float* __restrict__ out)
{
    const int b    = blockIdx.x;   // batch row
    const int lane = threadIdx.x;  // hidden index h

    __shared__ __align__(16) float xs[DPAD];
    __shared__ __align__(16) float h1s[H];
    __shared__ __align__(16) float h2s[H];
    __shared__ __align__(16) float hids[32];

    // ---- per-lane weights resident in VGPRs (loop-invariant) ----
    float wih0[DPAD];
    #pragma unroll
    for (int d = 0; d < DPAD; ++d)
        wih0[d] = (d < DIN) ? W_ih0[lane * DIN + d] : 0.0f;

    float whh0[H], wih1[H], whh1[H];
    #pragma unroll
    for (int k = 0; k < H; ++k) {
        whh0[k] = W_hh0[lane * H + k];
        wih1[k] = W_ih1[lane * H + k];
        whh1[k] = W_hh1[lane * H + k];
    }
    const float bias0 = b_ih0[lane] + b_hh0[lane];
    const float bias1 = b_ih1[lane] + b_hh1[lane];

    h1s[lane] = 0.0f;
    h2s[lane] = 0.0f;

    const float* __restrict__ xrow = x + (size_t)b * (size_t)S_LEN * DIN;

    // prefetch x row for s=0
    float xv_next = (lane < DIN) ? xrow[lane] : 0.0f;

    __syncthreads();

    for (int s = 0; s < S_LEN; ++s) {
        // stage current x row into LDS (lanes >= DIN carry 0 pad)
        if (lane < DPAD) xs[lane] = xv_next;
        __syncthreads();

        // issue next step's x load immediately — hides HBM latency under compute
        float xv_pref = 0.0f;
        if (s + 1 < S_LEN && lane < DIN) xv_pref = xrow[(size_t)(s + 1) * DIN + lane];

        // ---- stage 1: h1 = tanh(xp + h1 @ W_hh0^T) ----
        float a0 = bias0, a1 = 0.0f, a2 = 0.0f, a3 = 0.0f;
        #pragma unroll
        for (int q = 0; q < DPAD / 4; ++q) {
            float4 xv = *(const float4*)&xs[4 * q];
            a0 = fmaf(xv.x, wih0[4 * q + 0], a0);
            a1 = fmaf(xv.y, wih0[4 * q + 1], a1);
            a2 = fmaf(xv.z, wih0[4 * q + 2], a2);
            a3 = fmaf(xv.w, wih0[4 * q + 3], a3);
        }
        #pragma unroll
        for (int q = 0; q < H / 4; ++q) {
            float4 hv = *(const float4*)&h1s[4 * q];
            a0 = fmaf(hv.x, whh0[4 * q + 0], a0);
            a1 = fmaf(hv.y, whh0[4 * q + 1], a1);
            a2 = fmaf(hv.z, whh0[4 * q + 2], a2);
            a3 = fmaf(hv.w, whh0[4 * q + 3], a3);
        }
        float h1n = tanh_fast((a0 + a1) + (a2 + a3));

        __syncthreads();            // all reads of old h1 done
        h1s[lane] = h1n;
        __syncthreads();            // new h1 visible

        // ---- stage 2: h2 = tanh(h1_new @ W_ih1^T + h2 @ W_hh1^T + b) ----
        float c0 = bias1, c1 = 0.0f, c2 = 0.0f, c3 = 0.0f;
        #pragma unroll
        for (int q = 0; q < H / 4; ++q) {
            float4 hv = *(const float4*)&h1s[4 * q];
            c0 = fmaf(hv.x, wih1[4 * q + 0], c0);
            c1 = fmaf(hv.y, wih1[4 * q + 1], c1);
            c2 = fmaf(hv.z, wih1[4 * q + 2], c2);
            c3 = fmaf(hv.w, wih1[4 * q + 3], c3);
        }
        #pragma unroll
        for (int q = 0; q < H / 4; ++q) {
            float4 hv = *(const float4*)&h2s[4 * q];
            c0 = fmaf(hv.x, whh1[4 * q + 0], c0);
            c1 = fmaf(hv.y, whh1[4 * q + 1], c1);
            c2 = fmaf(hv.z, whh1[4 * q + 2], c2);
            c3 = fmaf(hv.w, whh1[4 * q + 3], c3);
        }
        float h2n = tanh_fast((c0 + c1) + (c2 + c3));

        __syncthreads();            // all reads of old h2 done
        h2s[lane] = h2n;

        xv_next = xv_pref;
        __syncthreads();            // new h2 visible before next step's stage 2
    }

    // ---- head: hidden = relu(h2 @ W1^T + b1); out = sigmoid(hidden @ W2^T + b2) ----
    if (lane < 32) {
        float a = b1[lane];
        #pragma unroll
        for (int k = 0; k < H; ++k)
            a = fmaf(h2s[k], W1[lane * H + k], a);
        hids[lane] = fmaxf(a, 0.0f);
    }
    __syncthreads();
    if (lane == 0) {
        float o = b2[0];
        #pragma unroll
        for (int j = 0; j < 32; ++j)
            o = fmaf(hids[j], W2[j], o);
        out[b] = 1.0f / (1.0f + __expf(-o));
    }
}

extern "C" void kernel_launch(void* const* d_in, const int* in_sizes, int n_in,
                              void* d_out, int out_size, void* d_ws, size_t ws_size,
                              hipStream_t stream) {
    const float* x     = (const float*)d_in[0];
    const float* W_ih0 = (const float*)d_in[1];
    const float* W_hh0 = (const float*)d_in[2];
    const float* b_ih0 = (const float*)d_in[3];
    const float* b_hh0 = (const float*)d_in[4];
    const float* W_ih1 = (const float*)d_in[5];
    const float* W_hh1 = (const float*)d_in[6];
    const float* b_ih1 = (const float*)d_in[7];
    const float* b_hh1 = (const float*)d_in[8];
    const float* W1    = (const float*)d_in[9];
    const float* b1    = (const float*)d_in[10];
    const float* W2    = (const float*)d_in[11];
    const float* b2    = (const float*)d_in[12];
    float* out = (float*)d_out;

    rnn_fused<<<dim3(512), dim3(64), 0, stream>>>(
        x, W_ih0, W_hh0, b_ih0, b_hh0,
        W_ih1, W_hh1, b_ih1, b_hh1,
        W1, b1, W2, b2, out);
}

// Round 2
// 1399.687 us; speedup vs baseline: 2.3517x; 2.3517x over previous
//
#include <hip/hip_runtime.h>

#define S_LEN 2048
#define DIN   50
#define H     64
#define NW    4      // waves per block (k-split)
#define DCH   13     // x-chunk per wave: 13*4 = 52 >= 50

// tanh(v) = 1 - 2/(exp(2v)+1); ~1e-6 rel err, exact at +/-inf
__device__ __forceinline__ float tanh_fast(float v) {
    float e = __expf(2.0f * v);
    return 1.0f - 2.0f * __builtin_amdgcn_rcpf(e + 1.0f);
}

__global__ __launch_bounds__(256, 2)
void rnn_fused(const float* __restrict__ x,
               const float* __restrict__ W_ih0, const float* __restrict__ W_hh0,
               const float* __restrict__ b_ih0, const float* __restrict__ b_hh0,
               const float* __restrict__ W_ih1, const float* __restrict__ W_hh1,
               const float* __restrict__ b_ih1, const float* __restrict__ b_hh1,
               const float* __restrict__ W1, const float* __restrict__ b1,
               const float* __restrict__ W2, const float* __restrict__ b2,
               float* __restrict__ out)
{
    const int b    = blockIdx.x;
    const int tid  = threadIdx.x;
    const int w    = tid >> 6;     // wave id: k-chunk owner
    const int lane = tid & 63;     // output unit

    __shared__ __align__(16) float xs[2][NW][16];   // x row, chunked+padded, dbl-buffered
    __shared__ __align__(16) float h1s[H];
    __shared__ __align__(16) float h2s[H];
    __shared__ __align__(16) float part1[NW][H];
    __shared__ __align__(16) float part2[NW][H];
    __shared__ float hids[32];

    // ---- per-lane weight chunks, register-resident (64 floats/lane) ----
    float wih0_l[16];
    #pragma unroll
    for (int j = 0; j < 16; ++j) {
        int c = DCH * w + j;
        wih0_l[j] = (j < DCH && c < DIN) ? W_ih0[lane * DIN + c] : 0.0f;
    }
    float whh0_l[16], wih1_l[16], whh1_l[16];
    #pragma unroll
    for (int j = 0; j < 16; ++j) {
        whh0_l[j] = W_hh0[lane * H + 16 * w + j];
        wih1_l[j] = W_ih1[lane * H + 16 * w + j];
        whh1_l[j] = W_hh1[lane * H + 16 * w + j];
    }
    const float bias0 = b_ih0[lane] + b_hh0[lane];
    const float bias1 = b_ih1[lane] + b_hh1[lane];

    const float* __restrict__ xrow = x + (size_t)b * (size_t)(S_LEN * DIN);

    // staging slot (wave 0 only): slot (sw, sj) <- x[s*DIN + DCH*sw + sj]
    const int  sw   = tid >> 4, sj = tid & 15;
    const int  scol = DCH * sw + sj;
    const bool sval = (tid < 64) && (sj < DCH) && (scol < DIN);

    // stage row 0; prefetch rows 1, 2 (depth-2 covers ~900cy HBM latency)
    if (tid < 64) xs[0][sw][sj] = sval ? xrow[scol] : 0.0f;
    float pfA = sval ? xrow[1 * DIN + scol] : 0.0f;   // row 1
    float pfB = sval ? xrow[2 * DIN + scol] : 0.0f;   // row 2

    h1s[lane] = 0.0f;   // all waves write identical zeros
    h2s[lane] = 0.0f;
    __syncthreads();

    // x-projection chunk for s=0
    float xacc;
    {
        float a0 = 0, a1 = 0, a2 = 0, a3 = 0;
        #pragma unroll
        for (int q = 0; q < 4; ++q) {
            float4 xv = *(const float4*)&xs[0][w][4 * q];
            a0 = fmaf(xv.x, wih0_l[4 * q + 0], a0);
            a1 = fmaf(xv.y, wih0_l[4 * q + 1], a1);
            a2 = fmaf(xv.z, wih0_l[4 * q + 2], a2);
            a3 = fmaf(xv.w, wih0_l[4 * q + 3], a3);
        }
        xacc = (a0 + a1) + (a2 + a3);
    }

    for (int s = 0; s < S_LEN; ++s) {
        const int nb = (s + 1) & 1;

        // ---- stage 1 partial: xacc + whh0-chunk . h1_old ----
        float a0 = xacc, a1 = 0, a2 = 0, a3 = 0;
        #pragma unroll
        for (int q = 0; q < 4; ++q) {
            float4 hv = *(const float4*)&h1s[16 * w + 4 * q];
            a0 = fmaf(hv.x, whh0_l[4 * q + 0], a0);
            a1 = fmaf(hv.y, whh0_l[4 * q + 1], a1);
            a2 = fmaf(hv.z, whh0_l[4 * q + 2], a2);
            a3 = fmaf(hv.w, whh0_l[4 * q + 3], a3);
        }
        part1[w][lane] = (a0 + a1) + (a2 + a3);

        // stage next x row; rotate prefetch (wave 0)
        if (tid < 64) xs[nb][sw][sj] = pfA;
        pfA = pfB;
        pfB = (sval && (s + 3) < S_LEN) ? xrow[(size_t)(s + 3) * DIN + scol] : 0.0f;

        __syncthreads();   // B1: partials + staged x visible

        // ---- reduce 1 (redundant in all waves -> identical h1n) ----
        float r1 = (part1[0][lane] + part1[1][lane]) + (part1[2][lane] + part1[3][lane]);
        float h1n = tanh_fast(r1 + bias0);
        h1s[lane] = h1n;   // every wave writes identical value -> own-wave RAW, no barrier

        // ---- x-projection for s+1 (independent of h; fills LDS-latency bubble) ----
        float xn0 = 0, xn1 = 0, xn2 = 0, xn3 = 0;
        #pragma unroll
        for (int q = 0; q < 4; ++q) {
            float4 xv = *(const float4*)&xs[nb][w][4 * q];
            xn0 = fmaf(xv.x, wih0_l[4 * q + 0], xn0);
            xn1 = fmaf(xv.y, wih0_l[4 * q + 1], xn1);
            xn2 = fmaf(xv.z, wih0_l[4 * q + 2], xn2);
            xn3 = fmaf(xv.w, wih0_l[4 * q + 3], xn3);
        }

        // ---- stage 2 partial: whh1-chunk . h2_old + wih1-chunk . h1_new ----
        float c0 = 0, c1 = 0, c2 = 0, c3 = 0;
        #pragma unroll
        for (int q = 0; q < 4; ++q) {
            float4 hv = *(const float4*)&h2s[16 * w + 4 * q];
            c0 = fmaf(hv.x, whh1_l[4 * q + 0], c0);
            c1 = fmaf(hv.y, whh1_l[4 * q + 1], c1);
            c2 = fmaf(hv.z, whh1_l[4 * q + 2], c2);
            c3 = fmaf(hv.w, whh1_l[4 * q + 3], c3);
        }
        #pragma unroll
        for (int q = 0; q < 4; ++q) {
            float4 hv = *(const float4*)&h1s[16 * w + 4 * q];  // fresh h1, own-wave write
            c0 = fmaf(hv.x, wih1_l[4 * q + 0], c0);
            c1 = fmaf(hv.y, wih1_l[4 * q + 1], c1);
            c2 = fmaf(hv.z, wih1_l[4 * q + 2], c2);
            c3 = fmaf(hv.w, wih1_l[4 * q + 3], c3);
        }
        part2[w][lane] = (c0 + c1) + (c2 + c3);

        __syncthreads();   // B2: partials visible

        // ---- reduce 2 ----
        float r2 = (part2[0][lane] + part2[1][lane]) + (part2[2][lane] + part2[3][lane]);
        float h2n = tanh_fast(r2 + bias1);
        h2s[lane] = h2n;   // identical across waves

        xacc = (xn0 + xn1) + (xn2 + xn3);
    }

    __syncthreads();

    // ---- head: relu(h2 @ W1^T + b1) -> sigmoid(. @ W2^T + b2) ----
    if (tid < 32) {
        float acc = b1[tid];
        #pragma unroll
        for (int k = 0; k < H; ++k)
            acc = fmaf(h2s[k], W1[tid * H + k], acc);
        hids[tid] = fmaxf(acc, 0.0f);
    }
    __syncthreads();
    if (tid == 0) {
        float o = b2[0];
        #pragma unroll
        for (int j = 0; j < 32; ++j)
            o = fmaf(hids[j], W2[j], o);
        out[b] = 1.0f / (1.0f + __expf(-o));
    }
}

extern "C" void kernel_launch(void* const* d_in, const int* in_sizes, int n_in,
                              void* d_out, int out_size, void* d_ws, size_t ws_size,
                              hipStream_t stream) {
    const float* x     = (const float*)d_in[0];
    const float* W_ih0 = (const float*)d_in[1];
    const float* W_hh0 = (const float*)d_in[2];
    const float* b_ih0 = (const float*)d_in[3];
    const float* b_hh0 = (const float*)d_in[4];
    const float* W_ih1 = (const float*)d_in[5];
    const float* W_hh1 = (const float*)d_in[6];
    const float* b_ih1 = (const float*)d_in[7];
    const float* b_hh1 = (const float*)d_in[8];
    const float* W1    = (const float*)d_in[9];
    const float* b1    = (const float*)d_in[10];
    const float* W2    = (const float*)d_in[11];
    const float* b2    = (const float*)d_in[12];
    float* out = (float*)d_out;

    rnn_fused<<<dim3(512), dim3(256), 0, stream>>>(
        x, W_ih0, W_hh0, b_ih0, b_hh0,
        W_ih1, W_hh1, b_ih1, b_hh1,
        W1, b1, W2, b2, out);
}